// Round 4
// baseline (162.287 us; speedup 1.0000x reference)
//
#include <hip/hip_runtime.h>

// Conv2D 3x3 stride-1 pad-1, C_IN=C_OUT=16, H=W=1024, fp32 in/out.
// Fused implicit-GEMM. v5: barrier-free single-wave blocks.
//  - Every round so far: all pipes ~12% busy regardless of block-level
//    phasing -> the block barrier convoys waves into 2-3 serial streams/CU.
//    Fix: 64-thread (1-wave) blocks, wave-private LDS, ZERO __syncthreads.
//    Grid 64x32 = 2048 blocks ~ 8+ resident/CU = 8 independent self-paced
//    memory streams per CU.
//  - Each block: 16-wide x 32-tall region = NT=2 tiles of 16x16 (18x18 with
//    halo). Per-wave pipeline: load(t0); pack+write(t0); issue load(t1);
//    compute(t0) [t1 in flight]; pack+write(t1); compute(t1).
//    LDS ordering: per-wave in-order DS ops + compiler waitcnt. No barrier.
//  - staging: float2 along W (18 cols = 9 aligned pairs -> 162 tasks, 3 per
//    lane). Halo cols are inside contiguous row segments (no scalar-halo
//    fetch blowup like round 3). Border blocks take a guarded scalar path.
//  - weights: per-lane register gather (40 loads from the hot 9KB filter,
//    L2-resident) -> a[5] v8s fragments; no weight LDS, no table build.
//  - LDS tile [px=row*18+col][ch16], 32B/px, 16B-chunk XOR swizzle
//    phys = c ^ ((c>>3)&7). Verified: makes ds_write (64B-stride lanes)
//    AND quad ds_reads bank-uniform (without it writes are 4-way).
//  - compute: 16 rows x 5 mfma_f32_16x16x32_bf16; D col=lane&15 = px col,
//    row=(lane>>4)*4+i = c_out.

#define HH 1024
#define WW 1024
#define CIN 16
#define HWP (HH * WW)
#define LPX 392                // 324 tile px + scratch, * 32B = 12544 B

typedef short v8s __attribute__((ext_vector_type(8)));
typedef float v4f __attribute__((ext_vector_type(4)));
typedef unsigned int u32;

// packed {bf16(hi)<<16 | bf16(lo)}, hardware RNE
__device__ __forceinline__ u32 cvt_pk_bf16(float lo, float hi) {
    u32 r;
    asm("v_cvt_pk_bf16_f32 %0, %1, %2" : "=v"(r) : "v"(lo), "v"(hi));
    return r;
}

__device__ __forceinline__ int swz(int c) { return c ^ ((c >> 3) & 7); }

__global__ __launch_bounds__(64, 2)
void conv3x3_wave(const float* __restrict__ x,
                  const float* __restrict__ wgt,
                  const float* __restrict__ bias,
                  float* __restrict__ out) {
    __shared__ __align__(16) unsigned short sm[LPX * 16];

    const int lane = threadIdx.x;
    const int m = lane & 15;       // A row (c_out) for frag build; D/B px col
    const int q = lane >> 4;       // k-quad
    const int w0 = blockIdx.x * 16;
    const int h0b = blockIdx.y * 32;

    // ---- weight fragments in registers (gather from hot 9KB, per block) ----
    // a[g5] element j = W[m][(t&1)*8+j][kh][kw], t = 4*g5+q, kh*3+kw = t>>1.
    v8s a[5];
    #pragma unroll
    for (int g5 = 0; g5 < 5; ++g5) {
        const int t = 4 * g5 + q;
        union { u32 u[4]; v8s v; } wv;
        if (t < 18) {
            const int base = m * 144 + (t & 1) * 72 + (t >> 1);
            #pragma unroll
            for (int jj = 0; jj < 4; ++jj) {
                const float lo = wgt[base + 18 * jj];      // j = 2jj
                const float hi = wgt[base + 18 * jj + 9];  // j = 2jj+1
                wv.u[jj] = cvt_pk_bf16(lo, hi);
            }
        } else {
            wv.u[0] = wv.u[1] = wv.u[2] = wv.u[3] = 0u;
        }
        a[g5] = wv.v;
    }

    float bl[4];
    #pragma unroll
    for (int i = 0; i < 4; ++i) bl[i] = bias[q * 4 + i];

    // ---- B-chunk offsets: chunk t = 4g+q, t<=17 -> (kh,kw,half) ----
    int Kofs[5];
    #pragma unroll
    for (int g5 = 0; g5 < 5; ++g5) {
        int t = 4 * g5 + q;
        int tt = t > 17 ? 17 : t;      // dead lanes use a harmless valid addr
        int khkw = tt >> 1;
        int kh = khkw / 3;
        int kw = khkw - 3 * kh;
        Kofs[g5] = (kh * 18 + m + kw) * 2 + (tt & 1);
    }

    const bool intW = (w0 != 0) && (w0 != WW - 16);

    // staged tile: 3 tasks x 16ch float2 (px pair). px = 2T, T = lane+64*it.
    float2 f[48];

    auto load_tile = [&](int h0) {
        const bool interior = intW && (h0 != 0) && (h0 != HH - 16);
        #pragma unroll
        for (int it = 0; it < 3; ++it) {
            const int T0 = lane + 64 * it;
            const int T = T0 < 162 ? T0 : 161;     // dup-clamp ragged tail
            const int r = T / 9;
            const int c = 2 * (T - 9 * r);
            const int gh = h0 - 1 + r;
            const int gw = w0 - 1 + c;
            float2* dst = f + it * 16;
            if (interior) {
                const float* p = x + (size_t)gh * WW + gw;
                #pragma unroll
                for (int ch = 0; ch < CIN; ++ch)
                    dst[ch] = *(const float2*)(p + (size_t)ch * HWP);
            } else {
                const bool okh = (unsigned)gh < (unsigned)HH;
                const bool ok0 = okh && (unsigned)gw < (unsigned)WW;
                const bool ok1 = okh && (unsigned)(gw + 1) < (unsigned)WW;
                const size_t b0 = (size_t)(okh ? gh : 0) * WW;
                #pragma unroll
                for (int ch = 0; ch < CIN; ++ch) {
                    const float* p = x + (size_t)ch * HWP + b0;
                    dst[ch].x = ok0 ? p[gw] : 0.f;
                    dst[ch].y = ok1 ? p[gw + 1] : 0.f;
                }
            }
        }
    };

    // px = 2T -> chunks 4T..4T+3 = (px0,h0)(px0,h1)(px1,h0)(px1,h1)
    auto write_tile = [&]() {
        #pragma unroll
        for (int it = 0; it < 3; ++it) {
            const int T0 = lane + 64 * it;
            const bool valid = T0 < 162;
            const int sl = lane >= 34 ? lane - 34 : 0;     // scratch slot
            const int cb = valid ? 4 * T0 : (648 + 4 * sl);
            const float2* s = f + it * 16;
            u32 pk[8], pk2[8];
            #pragma unroll
            for (int i = 0; i < 8; ++i) {
                pk[i]  = cvt_pk_bf16(s[2 * i].x, s[2 * i + 1].x);
                pk2[i] = cvt_pk_bf16(s[2 * i].y, s[2 * i + 1].y);
            }
            *(uint4*)(sm + swz(cb + 0) * 8) = *(uint4*)&pk[0];
            *(uint4*)(sm + swz(cb + 1) * 8) = *(uint4*)&pk[4];
            *(uint4*)(sm + swz(cb + 2) * 8) = *(uint4*)&pk2[0];
            *(uint4*)(sm + swz(cb + 3) * 8) = *(uint4*)&pk2[4];
        }
    };

    auto compute_tile = [&](int h0) {
        #pragma unroll 4
        for (int r = 0; r < 16; ++r) {
            v4f acc = {0.f, 0.f, 0.f, 0.f};
            #pragma unroll
            for (int g5 = 0; g5 < 5; ++g5) {
                const int ck = r * 36 + Kofs[g5];   // (r+kh)*18+m+kw chunks
                v8s b = *(const v8s*)(sm + swz(ck) * 8);
                acc = __builtin_amdgcn_mfma_f32_16x16x32_bf16(a[g5], b, acc, 0, 0, 0);
            }
            float* op = out + (size_t)(h0 + r) * WW + (w0 + m);
            #pragma unroll
            for (int i = 0; i < 4; ++i)
                op[(size_t)(q * 4 + i) * HWP] = acc[i] + bl[i];
        }
    };

    // ---- barrier-free per-wave pipeline ----
    load_tile(h0b);
    write_tile();              // waits t0 loads; pack+ds_write
    load_tile(h0b + 16);       // issue t1 loads (WAR-safe: pack already read f)
    compute_tile(h0b);         // t1 loads land underneath
    write_tile();              // t1 pack; ds_writes ordered after reads (in-order DS)
    compute_tile(h0b + 16);
}

extern "C" void kernel_launch(void* const* d_in, const int* in_sizes, int n_in,
                              void* d_out, int out_size, void* d_ws, size_t ws_size,
                              hipStream_t stream) {
    const float* x = (const float*)d_in[0];
    const float* w = (const float*)d_in[1];
    const float* b = (const float*)d_in[2];
    float* out = (float*)d_out;
    dim3 grid(WW / 16, HH / 32);
    conv3x3_wave<<<grid, dim3(64), 0, stream>>>(x, w, b, out);
}

// Round 5
// 122.347 us; speedup vs baseline: 1.3265x; 1.3265x over previous
//
#include <hip/hip_runtime.h>

// Conv2D 3x3 stride-1 pad-1, C_IN=C_OUT=16, H=W=1024, fp32 in/out.
// Fused implicit-GEMM. v6 = round-1 structure (best: byte-clean 64-wide
// cooperative staging, reg-held prefetch, 2 blocks/CU) with the barrier
// poison removed:
//  - DIAGNOSIS: __syncthreads() compiles to "s_waitcnt vmcnt(0) lgkmcnt(0);
//    s_barrier". Each thread carries 64 outstanding dword stores out of
//    compute_tile, so every barrier stalled ALL waves until ~64KB/tile of
//    stores ack'd through L2 (~2-6 Kcy/tile, whole-CU idle). That is why
//    every pipe sat at ~12% across rounds 0-3 regardless of pipelining.
//  - FIX: raw __builtin_amdgcn_s_barrier() with an lgkmcnt(0)-only drain
//    (LDS visibility) and sched_barrier fences. Global stores are never
//    waited (nothing reads `out`; HW drains at wave end). Prefetch loads
//    issued before barrier #1 genuinely stay in flight under compute(0);
//    the pack's compiler counted-vmcnt (clamped <=63) waits ~1 store max.
//  - everything else identical to round 1: weights -> bf16 LDS table,
//    [row][col][cin16] tile w/ 16B-chunk XOR swizzle, 5x K=32
//    mfma_f32_16x16x32_bf16 per output row, v_cvt_pk_bf16_f32 packing.

#define HH 1024
#define WW 1024
#define CIN 16
#define COUT 16
#define TW 64
#define TH 16
#define NT 2                   // vertical tiles per block
#define LROWS (TH + 2)
#define LCOLS (TW + 2)
#define PIX 16                 // shorts per pixel (32B = 2 chunks)
#define NPIX (LROWS * LCOLS)   // 1188

typedef short v8s __attribute__((ext_vector_type(8)));
typedef float v4f __attribute__((ext_vector_type(4)));
typedef unsigned int u32;

__device__ __forceinline__ unsigned short f32_bf16(float f) {
    union { float f; u32 u; } v;
    v.f = f;
    u32 u = v.u;
    u += 0x7fffu + ((u >> 16) & 1u);  // RNE
    return (unsigned short)(u >> 16);
}

// packed {bf16(hi)<<16 | bf16(lo)}, hardware RNE
__device__ __forceinline__ u32 cvt_pk_bf16(float lo, float hi) {
    u32 r;
    asm("v_cvt_pk_bf16_f32 %0, %1, %2" : "=v"(r) : "v"(lo), "v"(hi));
    return r;
}

__device__ __forceinline__ int swz(int c) { return c ^ ((c >> 3) & 7); }

// Workgroup barrier WITHOUT the vmcnt(0) store-drain __syncthreads adds.
// lgkmcnt(0): own ds_writes/ds_reads retired before crossing (visibility /
// WAR). sched_barrier(0) fences stop the scheduler hoisting LDS ops across
// the inline asm (rule: hipcc hoists reg-only/LDS ops past asm waitcnt).
__device__ __forceinline__ void wave_barrier() {
    __builtin_amdgcn_sched_barrier(0);
    asm volatile("s_waitcnt lgkmcnt(0)" ::: "memory");
    __builtin_amdgcn_sched_barrier(0);
    __builtin_amdgcn_s_barrier();
    __builtin_amdgcn_sched_barrier(0);
}

__global__ __launch_bounds__(256, 2)
void conv3x3_fused(const float* __restrict__ x,
                   const float* __restrict__ wgt,
                   const float* __restrict__ bias,
                   float* __restrict__ out) {
    __shared__ __align__(16) unsigned short sm[NPIX * PIX];   // 38016 B
    __shared__ __align__(16) unsigned short wsm[20 * 16 * 8]; // 5120 B

    const int tid = threadIdx.x;
    const int lane = tid & 63;
    const int wave = tid >> 6;
    const int h0a = blockIdx.y * (TH * NT);
    const int w0 = blockIdx.x * TW;

    // ---- weights: coalesced global -> bf16 LDS table [t][m][8] ----
    // wgt linear e = m*144 + c*9 + kh*3 + kw  (c = half*8 + j)
    if (tid < 32) ((uint4*)(wsm + 18 * 16 * 8))[tid] = make_uint4(0u, 0u, 0u, 0u);
    #pragma unroll
    for (int s = 0; s < 9; ++s) {
        const int e = s * 256 + tid;   // 0..2303
        const int m = e / 144;
        const int rem = e - m * 144;
        const int c = rem / 9;
        const int r9 = rem - c * 9;    // kh*3 + kw
        const int t = r9 * 2 + (c >> 3);
        wsm[(t * 16 + m) * 8 + (c & 7)] = f32_bf16(wgt[e]);
    }

    // ---- staging helpers: body task b (0..287) = (row, 4-px group) ----
    auto load_body = [&](int b, int h0, float4* f4) {
        const int r = b >> 4;
        const int j = b & 15;
        const int gh = h0 - 1 + r;
        if ((unsigned)gh < (unsigned)HH) {
            const float4* src = (const float4*)(x + (size_t)gh * WW + w0) + j;
            #pragma unroll
            for (int c = 0; c < CIN; ++c)
                f4[c] = src[(size_t)c * (HH * WW / 4)];
        } else {
            #pragma unroll
            for (int c = 0; c < CIN; ++c)
                f4[c] = make_float4(0.f, 0.f, 0.f, 0.f);
        }
    };
    auto write_body = [&](int b, const float4* f4) {
        const int r = b >> 4;
        const int j = b & 15;
        const int pbase = r * LCOLS + 1 + 4 * j;   // first of 4 pixels
        #pragma unroll
        for (int k = 0; k < 4; ++k) {
            u32 pk[8];
            #pragma unroll
            for (int i = 0; i < 8; ++i) {
                const float lo = ((const float*)&f4[2 * i])[k];
                const float hi = ((const float*)&f4[2 * i + 1])[k];
                pk[i] = cvt_pk_bf16(lo, hi);
            }
            #pragma unroll
            for (int half = 0; half < 2; ++half) {
                const int cc = 2 * pbase + 2 * k + half;
                *(uint4*)(sm + swz(cc) * 8) = *(uint4*)&pk[half * 4];
            }
        }
    };
    // ---- halo task h (0..35): r = h>>1, side = h&1 (1 px, 16 ch scalar) ----
    auto load_halo = [&](int h, int h0, float* f) {
        const int r = h >> 1;
        const int side = h & 1;
        const int gh = h0 - 1 + r;
        const int gw = side ? (w0 + TW) : (w0 - 1);
        if ((unsigned)gh < (unsigned)HH && (unsigned)gw < (unsigned)WW) {
            const float* src = x + (size_t)gh * WW + gw;
            #pragma unroll
            for (int c = 0; c < CIN; ++c) f[c] = src[(size_t)c * (HH * WW)];
        } else {
            #pragma unroll
            for (int c = 0; c < CIN; ++c) f[c] = 0.f;
        }
    };
    auto write_halo = [&](int h, const float* f) {
        const int r = h >> 1;
        const int side = h & 1;
        const int p = r * LCOLS + (side ? 65 : 0);
        u32 pk[8];
        #pragma unroll
        for (int i = 0; i < 8; ++i)
            pk[i] = cvt_pk_bf16(f[2 * i], f[2 * i + 1]);
        #pragma unroll
        for (int half = 0; half < 2; ++half) {
            const int cc = 2 * p + half;
            *(uint4*)(sm + swz(cc) * 8) = *(uint4*)&pk[half * 4];
        }
    };

    // ---- stage tile A (loads first, then pack+write, for latency overlap) ----
    {
        float4 f1[16];
        float4 f2[16];
        float fh[16];
        load_body(tid, h0a, f1);
        if (tid < 32) load_body(256 + tid, h0a, f2);
        else if (tid < 68) load_halo(tid - 32, h0a, fh);
        write_body(tid, f1);
        if (tid < 32) write_body(256 + tid, f2);
        else if (tid < 68) write_halo(tid - 32, fh);
    }

    const int m = lane & 15;       // c_out row of A == pixel index n of B/D
    const int q = lane >> 4;       // quad: supplies k = 8q..8q+7 of each MFMA
    const int colbase = wave * 16 + m;

    // ---- B-chunk offsets: chunk t = 4g+q, t<=17 -> (kh,kw,half) ----
    int Kofs[5];
    #pragma unroll
    for (int g5 = 0; g5 < 5; ++g5) {
        int t = 4 * g5 + q;
        int tt = t > 17 ? 17 : t;      // dead lanes use a harmless valid addr
        int khkw = tt >> 1;
        int kh = khkw / 3;
        int kw = khkw - 3 * kh;
        int half = tt & 1;
        Kofs[g5] = (kh * LCOLS + colbase + kw) * 2 + half;
    }
    float bl[4];
    #pragma unroll
    for (int i = 0; i < 4; ++i) bl[i] = bias[q * 4 + i];

    // ---- prefetch tile B into registers: issue BEFORE barrier #1 so the
    //      loads are in flight across it (raw barrier does NOT drain vmcnt)
    float4 p1[16];
    float4 p2[16];
    float ph[16];
    load_body(tid, h0a + TH, p1);
    if (tid < 32) load_body(256 + tid, h0a + TH, p2);
    else if (tid < 68) load_halo(tid - 32, h0a + TH, ph);
    __builtin_amdgcn_sched_barrier(0);   // don't let loads sink into compute

    wave_barrier();                      // #1: tile-A ds_writes visible

    // ---- A fragments from the LDS weight table (slots 18,19 are zero) ----
    v8s a[5];
    #pragma unroll
    for (int g5 = 0; g5 < 5; ++g5) {
        const int t = 4 * g5 + q;     // 0..19
        a[g5] = *(const v8s*)(wsm + (t * 16 + m) * 8);
    }

    // ---- compute: wave = 16-pixel column group, loop TH rows ----
    auto compute_tile = [&](int h0) {
        #pragma unroll 4
        for (int r = 0; r < TH; ++r) {
            v4f acc = {0.f, 0.f, 0.f, 0.f};
            #pragma unroll
            for (int g5 = 0; g5 < 5; ++g5) {
                const int c = r * (LCOLS * 2) + Kofs[g5];  // logical chunk
                v8s b = *(const v8s*)(sm + swz(c) * 8);
                acc = __builtin_amdgcn_mfma_f32_16x16x32_bf16(a[g5], b, acc, 0, 0, 0);
            }
            float* op = out + (size_t)(h0 + r) * WW + (w0 + colbase);
            #pragma unroll
            for (int i = 0; i < 4; ++i)
                op[(size_t)(q * 4 + i) * (HH * WW)] = acc[i] + bl[i];
        }
    };

    compute_tile(h0a);                 // tile-B loads in flight underneath;
                                       // stores issue and drain in background

    wave_barrier();                    // #2: all waves' tile-A ds_reads done
                                       //     (WAR) — stores NOT drained

    // ---- write tile B to LDS (loads landed long ago; counted vmcnt only) ----
    write_body(tid, p1);
    if (tid < 32) write_body(256 + tid, p2);
    else if (tid < 68) write_halo(tid - 32, ph);

    wave_barrier();                    // #3: tile-B ds_writes visible

    compute_tile(h0a + TH);
}

extern "C" void kernel_launch(void* const* d_in, const int* in_sizes, int n_in,
                              void* d_out, int out_size, void* d_ws, size_t ws_size,
                              hipStream_t stream) {
    const float* x = (const float*)d_in[0];
    const float* w = (const float*)d_in[1];
    const float* b = (const float*)d_in[2];
    float* out = (float*)d_out;
    dim3 grid(WW / TW, HH / (TH * NT));
    conv3x3_fused<<<grid, dim3(256), 0, stream>>>(x, w, b, out);
}